// Round 6
// baseline (690.779 us; speedup 1.0000x reference)
//
#include <hip/hip_runtime.h>
#include <math.h>

// RWKV single-token forward — ONE persistent kernel + LLC-warming prefetchers.
// Round-6 = round-4 compute structure (242 us, VGPR 80) + 64 prefetch-only
// blocks that stream all weights (+post2) into the memory-side Infinity Cache
// in consumption order, paced ~2 layers ahead via block-0's epoch flag.
// Compute blocks then service their phase-burst reads from LLC instead of
// cold HBM, and HBM runs continuously instead of at ~25% duty cycle.

constexpr int E = 1024;
constexpr int H = 4096;
constexpr int V = 50277;
constexpr int L = 12;
constexpr int NBLK = 256;   // compute blocks (barrier participants)
constexpr int NPF  = 64;    // prefetcher blocks
constexpr int NTHR = 512;
constexpr float LN_EPS = 9.999999747378752e-06f;

#define SCOPE_AGENT __HIP_MEMORY_SCOPE_AGENT

__device__ __forceinline__ void cstoref(float *p, float v) {
  __hip_atomic_store(p, v, __ATOMIC_RELAXED, SCOPE_AGENT);
}
__device__ __forceinline__ void cstoreu(unsigned *p, unsigned v) {
  __hip_atomic_store(p, v, __ATOMIC_RELAXED, SCOPE_AGENT);
}
__device__ __forceinline__ unsigned cloadu(const unsigned *p) {
  return __hip_atomic_load(p, __ATOMIC_RELAXED, SCOPE_AGENT);
}

// Coherent (LLC-point) wide loads for cross-block data.
__device__ __forceinline__ float2 cload2(const void *p) {
  float2 r;
  asm volatile("global_load_dwordx2 %0, %1, off sc0 sc1\n\t"
               "s_waitcnt vmcnt(0)"
               : "=&v"(r) : "v"(p) : "memory");
  return r;
}
__device__ __forceinline__ void cload4x2(float4 &r0, float4 &r1,
                                         const void *p0, const void *p1) {
  asm volatile("global_load_dwordx4 %0, %2, off sc0 sc1\n\t"
               "global_load_dwordx4 %1, %3, off sc0 sc1\n\t"
               "s_waitcnt vmcnt(0)"
               : "=&v"(r0), "=&v"(r1) : "v"(p0), "v"(p1) : "memory");
}

struct Args {
  const float *statea, *stateb, *statec, *stated, *pre;
  const float *ln1w, *ln1b, *ln2w, *ln2b;
  const float *ak, *ar, *av, *kk, *vv, *rr, *tf, *td, *ovv;
  const float *tmk, *tmr, *kf, *rf, *vf;
  const float *post0, *post1, *post2;
  const int *token;
  float *out;
  float *ws;        // coherent scratch: u[1024], sxx[1024], x[1024], km[4096]
  unsigned *flags;  // per-block arrival flags, stride 32 dwords (128 B)
};

__device__ __forceinline__ void bar_arrive(const Args &a, unsigned ep, int blk) {
  __syncthreads();
  if (threadIdx.x == 0) cstoreu(&a.flags[blk * 32], ep);
}

__device__ __forceinline__ void bar_wait(const Args &a, unsigned ep) {
  if (threadIdx.x < NBLK) {
    while (cloadu(&a.flags[threadIdx.x * 32]) < ep)
      __builtin_amdgcn_s_sleep(2);
  }
  __syncthreads();
}

__device__ __forceinline__ float wred(float v) {
#pragma unroll
  for (int off = 32; off; off >>= 1) v += __shfl_down(v, off, 64);
  return v;
}

__device__ __forceinline__ float dot4(float4 w, float4 x) {
  return w.x * x.x + w.y * x.y + w.z * x.z + w.w * x.w;
}

__device__ __forceinline__ float2 block_stats_v(float2 v, float *s_x, float *s_red,
                                                int tid, int lane, int wid) {
  reinterpret_cast<float2 *>(s_x)[tid] = v;
  float s = v.x + v.y, s2 = v.x * v.x + v.y * v.y;
#pragma unroll
  for (int off = 32; off; off >>= 1) {
    s += __shfl_down(s, off, 64);
    s2 += __shfl_down(s2, off, 64);
  }
  if (lane == 0) { s_red[wid] = s; s_red[8 + wid] = s2; }
  __syncthreads();
  float ts = 0.f, ts2 = 0.f;
#pragma unroll
  for (int i = 0; i < 8; ++i) { ts += s_red[i]; ts2 += s_red[8 + i]; }
  float m = ts * (1.0f / E);
  float var = ts2 * (1.0f / E) - m * m;
  return make_float2(m, rsqrtf(var + LN_EPS));
}

__device__ __forceinline__ void loadrow(float4 *d, const float4 *P, int r, int lane) {
  const float4 *p = P + (size_t)r * 256;
  d[0] = p[lane]; d[1] = p[lane + 64]; d[2] = p[lane + 128]; d[3] = p[lane + 192];
}

// ---------------- Prefetcher role: stream region into LLC ----------------
__device__ __forceinline__ float pf_region(const float *base, int n4, int gt) {
  const float4 *p = reinterpret_cast<const float4 *>(base);
  float s = 0.f;
#pragma unroll 2
  for (int i = gt; i < n4; i += NPF * NTHR) {
    float4 v = p[i];
    s += v.x + v.y + v.z + v.w;
  }
  return s;
}

__device__ void prefetch_role(const Args &a, int pb) {
  const int gt = pb * NTHR + threadIdx.x;  // 0..32767
  float s = 0.f;
  for (int l = 0; l < L; ++l) {
    if (l >= 3) {
      unsigned need = 4u * (unsigned)(l - 2);
      while (cloadu(&a.flags[0]) < need) __builtin_amdgcn_s_sleep(16);
    }
    const size_t mE = (size_t)l * E * E;      // E x E mats
    const size_t mH = (size_t)l * H * E;      // H x E / E x H mats
    s += pf_region(a.ak + mE, E * E / 4, gt);
    s += pf_region(a.av + mE, E * E / 4, gt);
    s += pf_region(a.ar + mE, E * E / 4, gt);
    s += pf_region(a.ovv + mE, E * E / 4, gt);
    s += pf_region(a.kf + mH, H * E / 4, gt);
    s += pf_region(a.rf + mE, E * E / 4, gt);
    s += pf_region(a.vf + mH, E * H / 4, gt);
  }
  // post2 (196 MB): stream while compute runs layers 8..11.
  {
    while (cloadu(&a.flags[0]) < 32u) __builtin_amdgcn_s_sleep(16);
    s += pf_region(a.post2, V * (E / 4), gt);
  }
  asm volatile("" :: "v"(s));  // keep loads live (no DCE), no store
}

__global__ __launch_bounds__(NTHR) void rwkv_fused(Args a) {
  __shared__ __align__(16) float s_a[4096];
  __shared__ __align__(16) float s_x[1024];
  __shared__ __align__(16) float s_y[1024];
  __shared__ float s_pp[24];
  __shared__ float s_red[16];
  __shared__ float s_rt[4];

  const int blk = blockIdx.x;
  if (blk >= NBLK) { prefetch_role(a, blk - NBLK); return; }

  const int tid = threadIdx.x;
  const int lane = tid & 63;
  const int wid = tid >> 6;        // 0..7
  const int rloc = wid >> 1;       // 0..3
  const int h = wid & 1;           // half of the row this wave owns
  const int grow = blk * 4 + rloc; // global E-row 0..1023

  float *ws_u = a.ws, *ws_sxx = a.ws + 1024, *ws_x = a.ws + 2048, *ws_km = a.ws + 3072;
  float *out_logits = a.out;
  float *out_aaa = a.out + V;
  float *out_bbb = out_aaa + L * E;
  float *out_ccc = out_bbb + L * E;
  float *out_ddd = out_ccc + L * E;

  const int tok = a.token[0];
  const float *pre_row = a.pre + (size_t)tok * E;
  const float4 *s4a = reinterpret_cast<const float4 *>(s_a);

  float4 pw[10];
  unsigned ep = 1;

  // initial prefetch: P1 weights for layer 0
  {
    const float4 *kr = reinterpret_cast<const float4 *>(a.ak + (size_t)grow * E);
    const float4 *vr = reinterpret_cast<const float4 *>(a.av + (size_t)grow * E);
    const float4 *rr = reinterpret_cast<const float4 *>(a.ar + (size_t)grow * E);
    int b0 = h * 128 + lane;
    pw[0] = kr[b0]; pw[1] = kr[b0 + 64];
    pw[2] = vr[b0]; pw[3] = vr[b0 + 64];
    pw[4] = rr[b0]; pw[5] = rr[b0 + 64];
    asm volatile("" ::: "memory");
  }

  for (int l = 0; l < L; ++l) {
    const size_t lE = (size_t)l * E;

    // ============ P1: LN1 + k/v/r matvecs + wkv elementwise ============
    {
      float2 v;
      if (l == 0) {
        v = reinterpret_cast<const float2 *>(pre_row)[tid];
      } else {
        v = cload2(reinterpret_cast<const float2 *>(ws_x) + tid);
      }
      float2 st = block_stats_v(v, s_x, s_red, tid, lane, wid);
#pragma unroll
      for (int j = 0; j < 2; ++j) {
        int e = tid + 512 * j;
        float xy = (s_x[e] - st.x) * st.y * a.ln1w[lE + e] + a.ln1b[lE + e];
        s_y[e] = xy;
        float sa = a.statea[lE + e];
        s_a[e] = xy + a.kk[lE + e] * sa;
        s_a[1024 + e] = xy + a.vv[lE + e] * sa;
        s_a[2048 + e] = xy + a.rr[lE + e] * sa;
      }
      __syncthreads();
      int b0 = h * 128 + lane;
      float accK = dot4(pw[0], s4a[b0]) + dot4(pw[1], s4a[b0 + 64]);
      float accV = dot4(pw[2], s4a[256 + b0]) + dot4(pw[3], s4a[256 + b0 + 64]);
      float accR = dot4(pw[4], s4a[512 + b0]) + dot4(pw[5], s4a[512 + b0 + 64]);
      accK = wred(accK); accV = wred(accV); accR = wred(accR);
      if (lane == 0) {
        s_pp[wid * 3 + 0] = accK;
        s_pp[wid * 3 + 1] = accV;
        s_pp[wid * 3 + 2] = accR;
      }
      __syncthreads();
      if (tid < 4) {
        size_t o = lE + blk * 4 + tid;
        float K = s_pp[(2 * tid) * 3] + s_pp[(2 * tid + 1) * 3];
        float Vv = s_pp[(2 * tid) * 3 + 1] + s_pp[(2 * tid + 1) * 3 + 1];
        float R = s_pp[(2 * tid) * 3 + 2] + s_pp[(2 * tid + 1) * 3 + 2];
        float kx = expf(K), rx = expf(R) + 1.0f;
        float etf = expf(a.tf[o]), etd = expf(a.td[o]);
        float sb = a.stateb[o], sc = a.statec[o];
        float w_ = sb + etf * kx * Vv;
        float d_ = sc * rx + etf * kx * rx;
        cstoref(&ws_u[blk * 4 + tid], w_ / (d_ + 0.001f));
        out_bbb[o] = sb * etd + kx * Vv;
        out_ccc[o] = sc * etd + kx;
        out_aaa[o] = s_y[blk * 4 + tid];
      }
    }
    bar_arrive(a, ep, blk);
    {
      const float4 *orow = reinterpret_cast<const float4 *>(a.ovv + (lE + grow) * E);
      int b0 = h * 128 + lane;
      pw[0] = orow[b0]; pw[1] = orow[b0 + 64];
      asm volatile("" ::: "memory");
    }
    bar_wait(a, ep); ++ep;

    // ============ P2: sxx = x + ovv @ u ============
    {
      reinterpret_cast<float2 *>(s_a)[tid] =
          cload2(reinterpret_cast<const float2 *>(ws_u) + tid);
      __syncthreads();
      int b0 = h * 128 + lane;
      float acc = dot4(pw[0], s4a[b0]) + dot4(pw[1], s4a[b0 + 64]);
      acc = wred(acc);
      if (lane == 0) s_pp[wid] = acc;
      __syncthreads();
      if (tid < 4) {
        float sxx = s_x[blk * 4 + tid] + s_pp[2 * tid] + s_pp[2 * tid + 1];
        cstoref(&ws_sxx[blk * 4 + tid], sxx);
      }
    }
    bar_arrive(a, ep, blk);
    {
      const float *kfb = a.kf + (size_t)l * H * E;
      const float4 *k0 = reinterpret_cast<const float4 *>(kfb + (size_t)(blk * 16 + wid) * E);
      const float4 *k1 = reinterpret_cast<const float4 *>(kfb + (size_t)(blk * 16 + 8 + wid) * E);
      pw[0] = k0[lane];       pw[1] = k0[lane + 64];
      pw[2] = k0[lane + 128]; pw[3] = k0[lane + 192];
      pw[4] = k1[lane];       pw[5] = k1[lane + 64];
      pw[6] = k1[lane + 128]; pw[7] = k1[lane + 192];
      const float4 *rrow = reinterpret_cast<const float4 *>(a.rf + (lE + grow) * E);
      int b0 = h * 128 + lane;
      pw[8] = rrow[b0]; pw[9] = rrow[b0 + 64];
      asm volatile("" ::: "memory");
    }
    bar_wait(a, ep); ++ep;

    // ============ P3: LN2 + key_ffn (2 rows/wave) + receptance_ffn ============
    {
      float2 v = cload2(reinterpret_cast<const float2 *>(ws_sxx) + tid);
      float2 st = block_stats_v(v, s_x, s_red, tid, lane, wid);
#pragma unroll
      for (int j = 0; j < 2; ++j) {
        int e = tid + 512 * j;
        float xx = (s_x[e] - st.x) * st.y * a.ln2w[lE + e] + a.ln2b[lE + e];
        s_y[e] = xx;
        float sd = a.stated[lE + e];
        s_a[e] = xx + a.tmk[lE + e] * sd;
        s_a[1024 + e] = xx + a.tmr[lE + e] * sd;
      }
      __syncthreads();
      float k0 = dot4(pw[0], s4a[lane]) + dot4(pw[1], s4a[lane + 64]) +
                 dot4(pw[2], s4a[lane + 128]) + dot4(pw[3], s4a[lane + 192]);
      float k1 = dot4(pw[4], s4a[lane]) + dot4(pw[5], s4a[lane + 64]) +
                 dot4(pw[6], s4a[lane + 128]) + dot4(pw[7], s4a[lane + 192]);
      int b0 = h * 128 + lane;
      float ar_ = dot4(pw[8], s4a[256 + b0]) + dot4(pw[9], s4a[256 + b0 + 64]);
      k0 = wred(k0); k1 = wred(k1); ar_ = wred(ar_);
      if (lane == 0) {
        float t0 = fmaxf(k0, 0.f), t1 = fmaxf(k1, 0.f);
        cstoref(&ws_km[blk * 16 + wid], t0 * t0);
        cstoref(&ws_km[blk * 16 + 8 + wid], t1 * t1);
        s_pp[wid] = ar_;
      }
      __syncthreads();
      if (tid < 4) {
        s_rt[tid] = expf(s_pp[2 * tid] + s_pp[2 * tid + 1]) + 1.0f;
        out_ddd[lE + blk * 4 + tid] = s_y[blk * 4 + tid];
      }
    }
    bar_arrive(a, ep, blk);
    {
      const float4 *vrow = reinterpret_cast<const float4 *>(a.vf + (lE + grow) * H);
      int b0 = h * 512 + lane;
      pw[0] = vrow[b0];       pw[1] = vrow[b0 + 64];
      pw[2] = vrow[b0 + 128]; pw[3] = vrow[b0 + 192];
      pw[4] = vrow[b0 + 256]; pw[5] = vrow[b0 + 320];
      pw[6] = vrow[b0 + 384]; pw[7] = vrow[b0 + 448];
      asm volatile("" ::: "memory");
    }
    bar_wait(a, ep); ++ep;

    // ============ P4: x_next = sxx + (vf @ km) / rt ============
    {
      float4 km0, km1;
      cload4x2(km0, km1,
               reinterpret_cast<const float4 *>(ws_km) + tid,
               reinterpret_cast<const float4 *>(ws_km) + tid + 512);
      reinterpret_cast<float4 *>(s_a)[tid] = km0;
      reinterpret_cast<float4 *>(s_a)[tid + 512] = km1;
      __syncthreads();
      int b0 = h * 512 + lane;
      float acc = dot4(pw[0], s4a[b0]) + dot4(pw[1], s4a[b0 + 64]) +
                  dot4(pw[2], s4a[b0 + 128]) + dot4(pw[3], s4a[b0 + 192]) +
                  dot4(pw[4], s4a[b0 + 256]) + dot4(pw[5], s4a[b0 + 320]) +
                  dot4(pw[6], s4a[b0 + 384]) + dot4(pw[7], s4a[b0 + 448]);
      acc = wred(acc);
      if (lane == 0) s_pp[wid] = acc;
      __syncthreads();
      if (tid < 4) {
        float xn = s_x[blk * 4 + tid] + (s_pp[2 * tid] + s_pp[2 * tid + 1]) / s_rt[tid];
        cstoref(&ws_x[blk * 4 + tid], xn);
      }
    }
    bar_arrive(a, ep, blk);
    if (l < L - 1) {
      const size_t lE2 = (size_t)(l + 1) * E;
      const float4 *kr = reinterpret_cast<const float4 *>(a.ak + (lE2 + grow) * E);
      const float4 *vr = reinterpret_cast<const float4 *>(a.av + (lE2 + grow) * E);
      const float4 *rr = reinterpret_cast<const float4 *>(a.ar + (lE2 + grow) * E);
      int b0 = h * 128 + lane;
      pw[0] = kr[b0]; pw[1] = kr[b0 + 64];
      pw[2] = vr[b0]; pw[3] = vr[b0 + 64];
      pw[4] = rr[b0]; pw[5] = rr[b0 + 64];
      asm volatile("" ::: "memory");
    }
    bar_wait(a, ep); ++ep;
  }

  // ============ Final: LN + logits = post2 @ xfin (double-buffered) ============
  {
    float2 v = cload2(reinterpret_cast<const float2 *>(ws_x) + tid);
    float2 st = block_stats_v(v, s_x, s_red, tid, lane, wid);
#pragma unroll
    for (int j = 0; j < 2; ++j) {
      int e = tid + 512 * j;
      s_a[e] = (s_x[e] - st.x) * st.y * a.post0[e] + a.post1[e];
    }
    __syncthreads();

    const float4 *P2 = reinterpret_cast<const float4 *>(a.post2);
    const int gw = blk * 8 + wid;  // 0..2047
    int r0 = gw, r1 = gw + 2048;
    float4 A0[4], A1[4];
    loadrow(A0, P2, r0, lane);
    loadrow(A1, P2, r1 < V ? r1 : r0, lane);
    while (true) {
      int n0 = r0 + 4096, n1 = n0 + 2048;
      bool more = n0 < V;
      float4 B0[4], B1[4];
      if (more) {
        loadrow(B0, P2, n0, lane);
        loadrow(B1, P2, n1 < V ? n1 : n0, lane);
      }
      float a0 = dot4(A0[0], s4a[lane]) + dot4(A0[1], s4a[lane + 64]) +
                 dot4(A0[2], s4a[lane + 128]) + dot4(A0[3], s4a[lane + 192]);
      float a1 = dot4(A1[0], s4a[lane]) + dot4(A1[1], s4a[lane + 64]) +
                 dot4(A1[2], s4a[lane + 128]) + dot4(A1[3], s4a[lane + 192]);
      a0 = wred(a0); a1 = wred(a1);
      if (lane == 0) {
        out_logits[r0] = a0;
        if (r1 < V) out_logits[r1] = a1;
      }
      if (!more) break;
#pragma unroll
      for (int q = 0; q < 4; ++q) { A0[q] = B0[q]; A1[q] = B1[q]; }
      r0 = n0; r1 = n1;
    }
  }
}

extern "C" void kernel_launch(void *const *d_in, const int *in_sizes, int n_in,
                              void *d_out, int out_size, void *d_ws, size_t ws_size,
                              hipStream_t stream) {
  (void)in_sizes; (void)n_in; (void)out_size; (void)ws_size;
  Args a;
  a.statea = (const float *)d_in[0];
  a.stateb = (const float *)d_in[1];
  a.statec = (const float *)d_in[2];
  a.stated = (const float *)d_in[3];
  a.pre    = (const float *)d_in[4];
  a.ln1w   = (const float *)d_in[5];
  a.ln1b   = (const float *)d_in[6];
  a.ln2w   = (const float *)d_in[7];
  a.ln2b   = (const float *)d_in[8];
  a.ak     = (const float *)d_in[9];
  a.ar     = (const float *)d_in[10];
  a.av     = (const float *)d_in[11];
  a.kk     = (const float *)d_in[12];
  a.vv     = (const float *)d_in[13];
  a.rr     = (const float *)d_in[14];
  a.tf     = (const float *)d_in[15];
  a.td     = (const float *)d_in[16];
  a.ovv    = (const float *)d_in[17];
  a.tmk    = (const float *)d_in[18];
  a.tmr    = (const float *)d_in[19];
  a.kf     = (const float *)d_in[20];
  a.rf     = (const float *)d_in[21];
  a.vf     = (const float *)d_in[22];
  a.post0  = (const float *)d_in[23];
  a.post1  = (const float *)d_in[24];
  a.post2  = (const float *)d_in[25];
  a.token  = (const int *)d_in[26];
  a.out    = (float *)d_out;

  a.flags  = (unsigned *)d_ws;                 // 256 flags, 128 B stride = 32 KB
  a.ws     = (float *)((char *)d_ws + 32768);  // coherent data vectors

  hipMemsetAsync(d_ws, 0, 32768, stream);
  rwkv_fused<<<NBLK + NPF, NTHR, 0, stream>>>(a);
}

// Round 7
// 266.839 us; speedup vs baseline: 2.5887x; 2.5887x over previous
//
#include <hip/hip_runtime.h>
#include <math.h>

// RWKV single-token forward — ONE persistent kernel (round-4 structure) +
// LDS double-buffered weight staging for the two big per-layer matrices.
//  - kf (64KB/block) staged via global_load_lds during P1+P2, consumed P3.
//  - vf (64KB/block) staged during P3, consumed P4. Buffers alternate by layer.
//  - Intra-phase syncs are lgkmcnt-only (raw s_barrier) so staging is never
//    drained mid-phase; it drains at bar_arrive's __syncthreads (end of phase),
//    i.e. fully overlapped with compute.
//  - Small matrices (ak/av/ar, ovv, rf) keep register prefetch; ak/av/ar issue
//    at P4 body top (~2.5us of cover before P1 consumption).
//  - Round-6 prefetcher blocks REMOVED (they doubled HBM fetch: 430->850MB).

constexpr int E = 1024;
constexpr int H = 4096;
constexpr int V = 50277;
constexpr int L = 12;
constexpr int NBLK = 256;
constexpr int NTHR = 512;
constexpr float LN_EPS = 9.999999747378752e-06f;

#define SCOPE_AGENT __HIP_MEMORY_SCOPE_AGENT

__device__ __forceinline__ void cstoref(float *p, float v) {
  __hip_atomic_store(p, v, __ATOMIC_RELAXED, SCOPE_AGENT);
}
__device__ __forceinline__ void cstoreu(unsigned *p, unsigned v) {
  __hip_atomic_store(p, v, __ATOMIC_RELAXED, SCOPE_AGENT);
}
__device__ __forceinline__ unsigned cloadu(const unsigned *p) {
  return __hip_atomic_load(p, __ATOMIC_RELAXED, SCOPE_AGENT);
}

// Coherent (LLC-point) loads for cross-block data. NOTE: contain vmcnt(0) —
// must be issued BEFORE any staging in the phase.
__device__ __forceinline__ float2 cload2(const void *p) {
  float2 r;
  asm volatile("global_load_dwordx2 %0, %1, off sc0 sc1\n\t"
               "s_waitcnt vmcnt(0)"
               : "=&v"(r) : "v"(p) : "memory");
  return r;
}
__device__ __forceinline__ void cload4x2(float4 &r0, float4 &r1,
                                         const void *p0, const void *p1) {
  asm volatile("global_load_dwordx4 %0, %2, off sc0 sc1\n\t"
               "global_load_dwordx4 %1, %3, off sc0 sc1\n\t"
               "s_waitcnt vmcnt(0)"
               : "=&v"(r0), "=&v"(r1) : "v"(p0), "v"(p1) : "memory");
}

// Async global->LDS staging: 64 lanes x 16B = 1KB per call.
// gp = per-lane global addr (base + lane*4 floats); lp = wave-uniform LDS base.
__device__ __forceinline__ void stage16(const float *gp, float *lp) {
  __builtin_amdgcn_global_load_lds(
      (const __attribute__((address_space(1))) void *)gp,
      (__attribute__((address_space(3))) void *)lp, 16, 0, 0);
}

// Workgroup barrier WITHOUT vmem drain (orders LDS only).
__device__ __forceinline__ void lds_sync() {
  asm volatile("s_waitcnt lgkmcnt(0)" ::: "memory");
  __builtin_amdgcn_s_barrier();
}

struct Args {
  const float *statea, *stateb, *statec, *stated, *pre;
  const float *ln1w, *ln1b, *ln2w, *ln2b;
  const float *ak, *ar, *av, *kk, *vv, *rr, *tf, *td, *ovv;
  const float *tmk, *tmr, *kf, *rf, *vf;
  const float *post0, *post1, *post2;
  const int *token;
  float *out;
  float *ws;        // coherent scratch: u[1024], sxx[1024], x[1024], km[4096]
  unsigned *flags;  // per-block arrival flags, stride 32 dwords (128 B)
};

// Arrive: __syncthreads drains vmem (coherent result stores + staging), then
// one flag store.
__device__ __forceinline__ void bar_arrive(const Args &a, unsigned ep, int blk) {
  __syncthreads();
  if (threadIdx.x == 0) cstoreu(&a.flags[blk * 32], ep);
}

// Wait: tid<256 poll one flag each; release with lgkm-only barrier so window
// prefetches stay in flight into the next phase.
__device__ __forceinline__ void bar_wait(const Args &a, unsigned ep) {
  if (threadIdx.x < NBLK) {
    while (cloadu(&a.flags[threadIdx.x * 32]) < ep)
      __builtin_amdgcn_s_sleep(2);
  }
  lds_sync();
}

__device__ __forceinline__ float wred(float v) {
#pragma unroll
  for (int off = 32; off; off >>= 1) v += __shfl_down(v, off, 64);
  return v;
}

__device__ __forceinline__ float dot4(float4 w, float4 x) {
  return w.x * x.x + w.y * x.y + w.z * x.z + w.w * x.w;
}

__device__ __forceinline__ float2 block_stats_v(float2 v, float *s_x, float *s_red,
                                                int tid, int lane, int wid) {
  reinterpret_cast<float2 *>(s_x)[tid] = v;
  float s = v.x + v.y, s2 = v.x * v.x + v.y * v.y;
#pragma unroll
  for (int off = 32; off; off >>= 1) {
    s += __shfl_down(s, off, 64);
    s2 += __shfl_down(s2, off, 64);
  }
  if (lane == 0) { s_red[wid] = s; s_red[8 + wid] = s2; }
  lds_sync();
  float ts = 0.f, ts2 = 0.f;
#pragma unroll
  for (int i = 0; i < 8; ++i) { ts += s_red[i]; ts2 += s_red[8 + i]; }
  float m = ts * (1.0f / E);
  float var = ts2 * (1.0f / E) - m * m;
  return make_float2(m, rsqrtf(var + LN_EPS));
}

__device__ __forceinline__ void loadrow(float4 *d, const float4 *P, int r, int lane) {
  const float4 *p = P + (size_t)r * 256;
  d[0] = p[lane]; d[1] = p[lane + 64]; d[2] = p[lane + 128]; d[3] = p[lane + 192];
}

__global__ __launch_bounds__(NTHR) void rwkv_fused(Args a) {
  __shared__ __align__(16) float wbuf[2][16384];  // 128 KB weight double-buffer
  __shared__ __align__(16) float s_a[4096];       // mix vectors / km staging
  __shared__ __align__(16) float s_x[1024];       // x / sxx (residual source)
  __shared__ float s_pp[24];
  __shared__ float s_red[16];
  __shared__ float s_rt[4];

  const int tid = threadIdx.x;
  const int lane = tid & 63;
  const int wid = tid >> 6;        // 0..7
  const int blk = blockIdx.x;
  const int rloc = wid >> 1;       // 0..3
  const int h = wid & 1;           // half of the row this wave owns
  const int grow = blk * 4 + rloc; // global E-row 0..1023
  const int b0h = h * 128 + lane;  // half-row float4 base

  float *ws_u = a.ws, *ws_sxx = a.ws + 1024, *ws_x = a.ws + 2048, *ws_km = a.ws + 3072;
  float *out_logits = a.out;
  float *out_aaa = a.out + V;
  float *out_bbb = out_aaa + L * E;
  float *out_ccc = out_bbb + L * E;
  float *out_ddd = out_ccc + L * E;

  const int tok = a.token[0];
  const float *pre_row = a.pre + (size_t)tok * E;
  const float4 *s4a = reinterpret_cast<const float4 *>(s_a);

  float4 pw1[6];   // ak/av/ar half-rows (issued in P4 body, consumed P1)
  float4 pwo[2];   // ovv half-row (P1 window -> P2)
  float4 pwr[2];   // rf half-row (P2 window -> P3)
  unsigned ep = 1;

  // Prologue: layer-0 P1 weights.
  {
    const float4 *kr = reinterpret_cast<const float4 *>(a.ak + (size_t)grow * E);
    const float4 *vr = reinterpret_cast<const float4 *>(a.av + (size_t)grow * E);
    const float4 *rr4 = reinterpret_cast<const float4 *>(a.ar + (size_t)grow * E);
    pw1[0] = kr[b0h]; pw1[1] = kr[b0h + 64];
    pw1[2] = vr[b0h]; pw1[3] = vr[b0h + 64];
    pw1[4] = rr4[b0h]; pw1[5] = rr4[b0h + 64];
    asm volatile("" ::: "memory");
  }

#pragma unroll 1
  for (int l = 0; l < L; ++l) {
    const size_t lE = (size_t)l * E;
    const float *kfb = a.kf + (size_t)l * H * E + (size_t)blk * 16 * E;

    // ============ P1: LN1 + k/v/r matvecs + wkv ============
    {
      float2 v;
      if (l == 0) v = reinterpret_cast<const float2 *>(pre_row)[tid];
      else        v = cload2(reinterpret_cast<const float2 *>(ws_x) + tid);
      // hoisted elementwise loads (issued BEFORE staging)
      float2 w1 = reinterpret_cast<const float2 *>(a.ln1w + lE)[tid];
      float2 b1 = reinterpret_cast<const float2 *>(a.ln1b + lE)[tid];
      float2 sa = reinterpret_cast<const float2 *>(a.statea + lE)[tid];
      float2 kk2 = reinterpret_cast<const float2 *>(a.kk + lE)[tid];
      float2 vv2 = reinterpret_cast<const float2 *>(a.vv + lE)[tid];
      float2 rr2 = reinterpret_cast<const float2 *>(a.rr + lE)[tid];
      float etf = 0.f, etd = 0.f, sb = 0.f, sc = 0.f;
      if (tid < 4) {
        size_t o = lE + blk * 4 + tid;
        etf = a.tf[o]; etd = a.td[o]; sb = a.stateb[o]; sc = a.statec[o];
      }
      // stage kf rows 0..7 (32KB) -> wbuf[l&1], overlapped with P1 compute
      {
        float *kb = wbuf[l & 1];
#pragma unroll
        for (int j = 0; j < 4; ++j) {
          int c = (wid * 4 + j) * 256;
          stage16(kfb + c + lane * 4, kb + c);
        }
      }
      float2 st = block_stats_v(v, s_x, s_red, tid, lane, wid);
      float2 xy = make_float2((v.x - st.x) * st.y * w1.x + b1.x,
                              (v.y - st.x) * st.y * w1.y + b1.y);
      if ((tid >> 1) == blk) {
        out_aaa[lE + 2 * tid] = xy.x;
        out_aaa[lE + 2 * tid + 1] = xy.y;
      }
      reinterpret_cast<float2 *>(s_a)[tid] =
          make_float2(xy.x + kk2.x * sa.x, xy.y + kk2.y * sa.y);
      reinterpret_cast<float2 *>(s_a + 1024)[tid] =
          make_float2(xy.x + vv2.x * sa.x, xy.y + vv2.y * sa.y);
      reinterpret_cast<float2 *>(s_a + 2048)[tid] =
          make_float2(xy.x + rr2.x * sa.x, xy.y + rr2.y * sa.y);
      lds_sync();
      float accK = dot4(pw1[0], s4a[b0h]) + dot4(pw1[1], s4a[b0h + 64]);
      float accV = dot4(pw1[2], s4a[256 + b0h]) + dot4(pw1[3], s4a[256 + b0h + 64]);
      float accR = dot4(pw1[4], s4a[512 + b0h]) + dot4(pw1[5], s4a[512 + b0h + 64]);
      accK = wred(accK); accV = wred(accV); accR = wred(accR);
      if (lane == 0) {
        s_pp[wid * 3 + 0] = accK;
        s_pp[wid * 3 + 1] = accV;
        s_pp[wid * 3 + 2] = accR;
      }
      lds_sync();
      if (tid < 4) {
        size_t o = lE + blk * 4 + tid;
        float K = s_pp[(2 * tid) * 3] + s_pp[(2 * tid + 1) * 3];
        float Vv = s_pp[(2 * tid) * 3 + 1] + s_pp[(2 * tid + 1) * 3 + 1];
        float R = s_pp[(2 * tid) * 3 + 2] + s_pp[(2 * tid + 1) * 3 + 2];
        float kx = expf(K), rx = expf(R) + 1.0f;
        float etf_ = expf(etf), etd_ = expf(etd);
        float w_ = sb + etf_ * kx * Vv;
        float d_ = sc * rx + etf_ * kx * rx;
        cstoref(&ws_u[blk * 4 + tid], w_ / (d_ + 0.001f));
        out_bbb[o] = sb * etd_ + kx * Vv;
        out_ccc[o] = sc * etd_ + kx;
      }
    }
    bar_arrive(a, ep, blk);
    { // window: ovv half-row -> regs (consumed P2)
      const float4 *orow = reinterpret_cast<const float4 *>(a.ovv + (lE + grow) * E);
      pwo[0] = orow[b0h]; pwo[1] = orow[b0h + 64];
      asm volatile("" ::: "memory");
    }
    bar_wait(a, ep); ++ep;

    // ============ P2: sxx = x + ovv @ u ============
    {
      float2 u2 = cload2(reinterpret_cast<const float2 *>(ws_u) + tid);
      // stage kf rows 8..15 (32KB)
      {
        float *kb = wbuf[l & 1];
#pragma unroll
        for (int j = 0; j < 4; ++j) {
          int c = (32 + wid * 4 + j) * 256;
          stage16(kfb + c + lane * 4, kb + c);
        }
      }
      reinterpret_cast<float2 *>(s_a)[tid] = u2;
      lds_sync();
      float acc = dot4(pwo[0], s4a[b0h]) + dot4(pwo[1], s4a[b0h + 64]);
      acc = wred(acc);
      if (lane == 0) s_pp[wid] = acc;
      lds_sync();
      if (tid < 4) {
        float sxx = s_x[blk * 4 + tid] + s_pp[2 * tid] + s_pp[2 * tid + 1];
        cstoref(&ws_sxx[blk * 4 + tid], sxx);
      }
    }
    bar_arrive(a, ep, blk);
    { // window: rf half-row -> regs (consumed P3)
      const float4 *rrow = reinterpret_cast<const float4 *>(a.rf + (lE + grow) * E);
      pwr[0] = rrow[b0h]; pwr[1] = rrow[b0h + 64];
      asm volatile("" ::: "memory");
    }
    bar_wait(a, ep); ++ep;

    // ============ P3: LN2 + key_ffn (LDS) + receptance_ffn ============
    {
      float2 vsx = cload2(reinterpret_cast<const float2 *>(ws_sxx) + tid);
      float2 w2 = reinterpret_cast<const float2 *>(a.ln2w + lE)[tid];
      float2 b2 = reinterpret_cast<const float2 *>(a.ln2b + lE)[tid];
      float2 sd2 = reinterpret_cast<const float2 *>(a.stated + lE)[tid];
      float2 tk2 = reinterpret_cast<const float2 *>(a.tmk + lE)[tid];
      float2 tr2 = reinterpret_cast<const float2 *>(a.tmr + lE)[tid];
      // stage vf (64KB) -> wbuf[(l+1)&1], overlapped with P3 compute
      {
        const float *vfb = a.vf + (size_t)l * E * H + (size_t)blk * 4 * H;
        float *vb = wbuf[(l + 1) & 1];
#pragma unroll
        for (int j = 0; j < 8; ++j) {
          int c = (wid * 8 + j) * 256;
          stage16(vfb + c + lane * 4, vb + c);
        }
      }
      float2 st = block_stats_v(vsx, s_x, s_red, tid, lane, wid);
      float2 xx = make_float2((vsx.x - st.x) * st.y * w2.x + b2.x,
                              (vsx.y - st.x) * st.y * w2.y + b2.y);
      if ((tid >> 1) == blk) {
        out_ddd[lE + 2 * tid] = xx.x;
        out_ddd[lE + 2 * tid + 1] = xx.y;
      }
      reinterpret_cast<float2 *>(s_a)[tid] =
          make_float2(xx.x + tk2.x * sd2.x, xx.y + tk2.y * sd2.y);
      reinterpret_cast<float2 *>(s_a + 1024)[tid] =
          make_float2(xx.x + tr2.x * sd2.x, xx.y + tr2.y * sd2.y);
      lds_sync();
      const float4 *kL = reinterpret_cast<const float4 *>(wbuf[l & 1]);
      float k0 = 0.f, k1 = 0.f;
#pragma unroll
      for (int it = 0; it < 4; ++it) {
        float4 xv = s4a[it * 64 + lane];
        k0 += dot4(kL[wid * 256 + it * 64 + lane], xv);
        k1 += dot4(kL[(wid + 8) * 256 + it * 64 + lane], xv);
      }
      float ar_ = dot4(pwr[0], s4a[256 + b0h]) + dot4(pwr[1], s4a[256 + b0h + 64]);
      k0 = wred(k0); k1 = wred(k1); ar_ = wred(ar_);
      if (lane == 0) {
        float t0 = fmaxf(k0, 0.f), t1 = fmaxf(k1, 0.f);
        cstoref(&ws_km[blk * 16 + wid], t0 * t0);
        cstoref(&ws_km[blk * 16 + 8 + wid], t1 * t1);
        s_pp[wid] = ar_;
      }
      lds_sync();
      if (tid < 4) {
        s_rt[tid] = expf(s_pp[2 * tid] + s_pp[2 * tid + 1]) + 1.0f;
      }
    }
    bar_arrive(a, ep, blk);
    bar_wait(a, ep); ++ep;

    // ============ P4: x_next = sxx + (vf @ km) / rt ============
    {
      float4 km0, km1;
      cload4x2(km0, km1,
               reinterpret_cast<const float4 *>(ws_km) + tid,
               reinterpret_cast<const float4 *>(ws_km) + tid + 512);
      // prefetch next layer's P1 weights NOW (hidden under P4 + barrier)
      if (l < L - 1) {
        const size_t lE2 = (size_t)(l + 1) * E;
        const float4 *kr = reinterpret_cast<const float4 *>(a.ak + (lE2 + grow) * E);
        const float4 *vr = reinterpret_cast<const float4 *>(a.av + (lE2 + grow) * E);
        const float4 *rr4 = reinterpret_cast<const float4 *>(a.ar + (lE2 + grow) * E);
        pw1[0] = kr[b0h]; pw1[1] = kr[b0h + 64];
        pw1[2] = vr[b0h]; pw1[3] = vr[b0h + 64];
        pw1[4] = rr4[b0h]; pw1[5] = rr4[b0h + 64];
        asm volatile("" ::: "memory");
      }
      reinterpret_cast<float4 *>(s_a)[tid] = km0;
      reinterpret_cast<float4 *>(s_a)[tid + 512] = km1;
      lds_sync();
      const float4 *vL = reinterpret_cast<const float4 *>(wbuf[(l + 1) & 1]);
      const int vb0 = rloc * 1024 + h * 512 + lane;
      const int sb0 = h * 512 + lane;
      float acc = 0.f;
#pragma unroll
      for (int it = 0; it < 8; ++it)
        acc += dot4(vL[vb0 + it * 64], s4a[sb0 + it * 64]);
      acc = wred(acc);
      if (lane == 0) s_pp[wid] = acc;
      lds_sync();
      if (tid < 4) {
        float xn = s_x[blk * 4 + tid] + (s_pp[2 * tid] + s_pp[2 * tid + 1]) / s_rt[tid];
        cstoref(&ws_x[blk * 4 + tid], xn);
      }
    }
    bar_arrive(a, ep, blk);
    bar_wait(a, ep); ++ep;
  }

  // ============ Final: LN + logits = post2 @ xfin (double-buffered) ============
  {
    float2 v = cload2(reinterpret_cast<const float2 *>(ws_x) + tid);
    float2 p0 = reinterpret_cast<const float2 *>(a.post0)[tid];
    float2 p1 = reinterpret_cast<const float2 *>(a.post1)[tid];
    float2 st = block_stats_v(v, s_x, s_red, tid, lane, wid);
    reinterpret_cast<float2 *>(s_a)[tid] =
        make_float2((v.x - st.x) * st.y * p0.x + p1.x,
                    (v.y - st.x) * st.y * p0.y + p1.y);
    lds_sync();

    const float4 *P2 = reinterpret_cast<const float4 *>(a.post2);
    const int gw = blk * 8 + wid;  // 0..2047
    int r0 = gw, r1 = gw + 2048;
    float4 A0[4], A1[4];
    loadrow(A0, P2, r0, lane);
    loadrow(A1, P2, r1 < V ? r1 : r0, lane);
    while (true) {
      int n0 = r0 + 4096, n1 = n0 + 2048;
      bool more = n0 < V;
      float4 B0[4], B1[4];
      if (more) {
        loadrow(B0, P2, n0, lane);
        loadrow(B1, P2, n1 < V ? n1 : n0, lane);
      }
      float a0 = dot4(A0[0], s4a[lane]) + dot4(A0[1], s4a[lane + 64]) +
                 dot4(A0[2], s4a[lane + 128]) + dot4(A0[3], s4a[lane + 192]);
      float a1 = dot4(A1[0], s4a[lane]) + dot4(A1[1], s4a[lane + 64]) +
                 dot4(A1[2], s4a[lane + 128]) + dot4(A1[3], s4a[lane + 192]);
      a0 = wred(a0); a1 = wred(a1);
      if (lane == 0) {
        out_logits[r0] = a0;
        if (r1 < V) out_logits[r1] = a1;
      }
      if (!more) break;
#pragma unroll
      for (int q = 0; q < 4; ++q) { A0[q] = B0[q]; A1[q] = B1[q]; }
      r0 = n0; r1 = n1;
    }
  }
}

extern "C" void kernel_launch(void *const *d_in, const int *in_sizes, int n_in,
                              void *d_out, int out_size, void *d_ws, size_t ws_size,
                              hipStream_t stream) {
  (void)in_sizes; (void)n_in; (void)out_size; (void)ws_size;
  Args a;
  a.statea = (const float *)d_in[0];
  a.stateb = (const float *)d_in[1];
  a.statec = (const float *)d_in[2];
  a.stated = (const float *)d_in[3];
  a.pre    = (const float *)d_in[4];
  a.ln1w   = (const float *)d_in[5];
  a.ln1b   = (const float *)d_in[6];
  a.ln2w   = (const float *)d_in[7];
  a.ln2b   = (const float *)d_in[8];
  a.ak     = (const float *)d_in[9];
  a.ar     = (const float *)d_in[10];
  a.av     = (const float *)d_in[11];
  a.kk     = (const float *)d_in[12];
  a.vv     = (const float *)d_in[13];
  a.rr     = (const float *)d_in[14];
  a.tf     = (const float *)d_in[15];
  a.td     = (const float *)d_in[16];
  a.ovv    = (const float *)d_in[17];
  a.tmk    = (const float *)d_in[18];
  a.tmr    = (const float *)d_in[19];
  a.kf     = (const float *)d_in[20];
  a.rf     = (const float *)d_in[21];
  a.vf     = (const float *)d_in[22];
  a.post0  = (const float *)d_in[23];
  a.post1  = (const float *)d_in[24];
  a.post2  = (const float *)d_in[25];
  a.token  = (const int *)d_in[26];
  a.out    = (float *)d_out;

  a.flags  = (unsigned *)d_ws;                 // 256 flags, 128 B stride = 32 KB
  a.ws     = (float *)((char *)d_ws + 32768);  // coherent data vectors

  hipMemsetAsync(d_ws, 0, 32768, stream);
  rwkv_fused<<<NBLK, NTHR, 0, stream>>>(a);
}